// Round 7
// baseline (86.635 us; speedup 1.0000x reference)
//
#include <hip/hip_runtime.h>
#include <math.h>

#define BATCH 8192
#define NLEN 4096

typedef float floatx4 __attribute__((ext_vector_type(4)));

__device__ inline floatx4 nt_load4(const float* p) {
    return __builtin_nontemporal_load(reinterpret_cast<const floatx4*>(p));
}

// ---------------------------------------------------------------------------
// Kernel 1: ONE WAVE PER ROW (4 rows per 256-thread block). Lane l owns the
// contiguous 64-element chunk [l*64, l*64+64). Branchless inner loop
// (padding is exactly 0.0f -> sum/sumsq unmasked; diffs via cndmask chains).
// NONTEMPORAL loads: rr is a 128 MiB zero-reuse stream; nt bypasses L2
// allocation. 2-half staging keeps VGPRs low (~8 waves/SIMD resident).
// One cross-lane boundary fixup per wave (ballot + variable shuffle).
// ---------------------------------------------------------------------------
__global__ __launch_bounds__(256) void hrv_feats_kernel(
    const float* __restrict__ rr, float* __restrict__ feats) {
    const int lane = threadIdx.x & 63;
    const int wid = threadIdx.x >> 6;
    const int row = blockIdx.x * 4 + wid;
    const float* r = rr + (size_t)row * NLEN + lane * 64;

    double dsum = 0.0, dsumsq = 0.0, dsumd2 = 0.0;
    int cnt = 0, nn50 = 0;
    float prev = 0.f, first = 0.f;
    bool has = false;

    float x[32];
    floatx4* xv = reinterpret_cast<floatx4*>(x);

#pragma unroll
    for (int half = 0; half < 2; ++half) {
#pragma unroll
        for (int i = 0; i < 8; ++i) xv[i] = nt_load4(r + (half * 8 + i) * 4);
#pragma unroll
        for (int c = 0; c < 2; ++c) {
            float s = 0.f, s2 = 0.f, d2 = 0.f;  // f32 partials over 16 elems
#pragma unroll
            for (int i = 0; i < 16; ++i) {
                const float v = x[c * 16 + i];
                const bool valid = v > 0.f;
                s += v;                    // padding is exactly 0 -> no mask
                s2 = fmaf(v, v, s2);
                cnt += valid ? 1 : 0;
                const float d = v - prev;  // same f32 sub as reference
                const float dm = (valid && has) ? d : 0.f;
                d2 = fmaf(dm, dm, d2);
                nn50 += (fabsf(dm) > 0.05f) ? 1 : 0;
                first = (valid && !has) ? v : first;
                prev = valid ? v : prev;
                has = has || valid;
            }
            dsum += s;
            dsumsq += s2;
            dsumd2 += d2;
        }
    }

    // boundary diff: my first valid vs last valid of nearest lower lane
    unsigned long long m = __ballot(has);
    unsigned long long pm = m & ((1ull << lane) - 1ull);  // lane0 -> 0
    int j = 63 - __clzll(pm | 1ull);
    float lastj = __shfl(prev, j, 64);
    if (has && pm) {
        float d = first - lastj;
        dsumd2 += (double)(d * d);
        nn50 += (fabsf(d) > 0.05f) ? 1 : 0;
    }

    // xor-butterfly reduction: ALL lanes end with totals (lanes 0-5 store)
#pragma unroll
    for (int off = 32; off; off >>= 1) {
        dsum += __shfl_xor(dsum, off, 64);
        dsumsq += __shfl_xor(dsumsq, off, 64);
        dsumd2 += __shfl_xor(dsumd2, off, 64);
        cnt += __shfl_xor(cnt, off, 64);
        nn50 += __shfl_xor(nn50, off, 64);
    }

    const float cntf = (float)cnt;
    const float denom_m = fmaxf(cntf, 1.f);
    const float mean = (float)(dsum / (double)denom_m);
    const float varsum = (float)(dsumsq - (double)cnt * (double)mean * (double)mean);
    const float denom_v = fmaxf(cntf - 1.f, 1.f);
    const float sdnn = sqrtf(fmaxf(varsum / denom_v, 0.f));
    const float rmssd = sqrtf(fmaxf((float)(dsumd2 / (double)denom_v), 0.f));
    const float pnn50 = (float)nn50 / denom_v;
    const float hr = 60.f / fmaxf(mean, 1e-12f);
    const float cv = sdnn / fmaxf(mean, 1e-12f);

    float val = mean;  // lane 0
    val = (lane == 1) ? sdnn : val;
    val = (lane == 2) ? rmssd : val;
    val = (lane == 3) ? pnn50 : val;
    val = (lane == 4) ? hr : val;
    val = (lane == 5) ? cv : val;
    if (cnt <= 1) val = 0.f;
    // COLUMN-MAJOR: feats[c][row] -> coalesced reads in kernel 2
    if (lane < 6) feats[lane * BATCH + row] = val;
}

// ---------------------------------------------------------------------------
// Kernel 2 (fused col-stats + MLP): 32 blocks x 1024 THREADS.
// Stats phase: per thread only 12 independent float4 loads (2 per column),
// all issued upfront, 16 waves/block to hide LLC/HBM latency (feats no
// longer sits in the reading CU's L2 after the kernel boundary). f64 accum
// for the (sumsq - B*mean^2) cancellation. Deterministic identical stats
// per block. MLP phase: threads 0..255 each handle one row.
// ---------------------------------------------------------------------------
__global__ __launch_bounds__(1024) void stats_mlp_kernel(
    const float* __restrict__ feats,
    const float* __restrict__ w1, const float* __restrict__ b1,
    const float* __restrict__ w2, const float* __restrict__ b2,
    float* __restrict__ out) {
    __shared__ double sh_s[16][6], sh_s2[16][6];
    __shared__ float sh_m[16][6];
    __shared__ float sh_stats[18];  // mean[6], std[6], max[6]

    const int t = threadIdx.x;

    // ---- stats: 12 independent float4 loads (2 per column) ----
    float4 f4[6][2];
#pragma unroll
    for (int c = 0; c < 6; ++c) {
        const float4* col = reinterpret_cast<const float4*>(feats + c * BATCH);
#pragma unroll
        for (int k = 0; k < 2; ++k) f4[c][k] = col[t + k * 1024];
    }
    double s[6], s2[6];
    float mx[6];
#pragma unroll
    for (int c = 0; c < 6; ++c) {
        const float f[8] = {f4[c][0].x, f4[c][0].y, f4[c][0].z, f4[c][0].w,
                            f4[c][1].x, f4[c][1].y, f4[c][1].z, f4[c][1].w};
        s[c] = 0.0; s2[c] = 0.0; mx[c] = -INFINITY;
#pragma unroll
        for (int k = 0; k < 8; ++k) {
            s[c] += (double)f[k];
            s2[c] += (double)f[k] * (double)f[k];
            mx[c] = fmaxf(mx[c], f[k]);
        }
    }
#pragma unroll
    for (int off = 32; off; off >>= 1) {
#pragma unroll
        for (int c = 0; c < 6; ++c) {
            s[c] += __shfl_down(s[c], off, 64);
            s2[c] += __shfl_down(s2[c], off, 64);
            mx[c] = fmaxf(mx[c], __shfl_down(mx[c], off, 64));
        }
    }
    if ((t & 63) == 0) {
        const int w = t >> 6;
#pragma unroll
        for (int c = 0; c < 6; ++c) {
            sh_s[w][c] = s[c];
            sh_s2[w][c] = s2[c];
            sh_m[w][c] = mx[c];
        }
    }
    __syncthreads();
    if (t < 6) {
        double S = 0, S2 = 0;
        float M = -INFINITY;
#pragma unroll
        for (int w = 0; w < 16; ++w) {
            S += sh_s[w][t];
            S2 += sh_s2[w][t];
            M = fmaxf(M, sh_m[w][t]);
        }
        const double meanb = S / (double)BATCH;
        double var = (S2 - (double)BATCH * meanb * meanb) / (double)(BATCH - 1);
        if (var < 0.0) var = 0.0;
        sh_stats[t] = (float)meanb;
        sh_stats[6 + t] = (float)sqrt(var);
        sh_stats[12 + t] = M;
    }
    __syncthreads();

    // ---- MLP: threads 0..255, one row each ----
    if (t < 256) {
        const int row = blockIdx.x * 256 + t;
        float f[6];
#pragma unroll
        for (int c = 0; c < 6; ++c) {
            float v = feats[c * BATCH + row];
            if (sh_stats[12 + c] > 0.f)
                v = (v - sh_stats[c]) / (sh_stats[6 + c] + 1e-8f);
            f[c] = v;
        }
        float h[16];
#pragma unroll
        for (int jj = 0; jj < 16; ++jj) {
            float a = b1[jj];
#pragma unroll
            for (int c = 0; c < 6; ++c) a = fmaf(f[c], w1[c * 16 + jj], a);
            h[jj] = fmaxf(a, 0.f);
        }
        float o[32];
#pragma unroll
        for (int k = 0; k < 32; ++k) o[k] = b2[k];
#pragma unroll
        for (int jj = 0; jj < 16; ++jj) {
            const float hj = h[jj];
#pragma unroll
            for (int k = 0; k < 32; ++k) o[k] = fmaf(hj, w2[jj * 32 + k], o[k]);
        }
        float4* ov = reinterpret_cast<float4*>(out + (size_t)row * 32);
        const float4* op = reinterpret_cast<const float4*>(o);
#pragma unroll
        for (int i = 0; i < 8; ++i) ov[i] = op[i];
    }
}

extern "C" void kernel_launch(void* const* d_in, const int* in_sizes, int n_in,
                              void* d_out, int out_size, void* d_ws, size_t ws_size,
                              hipStream_t stream) {
    const float* rr = (const float*)d_in[0];
    const float* w1 = (const float*)d_in[1];
    const float* b1 = (const float*)d_in[2];
    const float* w2 = (const float*)d_in[3];
    const float* b2 = (const float*)d_in[4];
    float* out = (float*)d_out;
    float* feats = (float*)d_ws;  // column-major [6][BATCH] = 192 KiB

    hrv_feats_kernel<<<BATCH / 4, 256, 0, stream>>>(rr, feats);
    stats_mlp_kernel<<<BATCH / 256, 1024, 0, stream>>>(feats, w1, b1, w2, b2, out);
}